// Round 18
// baseline (661.296 us; speedup 1.0000x reference)
//
#include <hip/hip_runtime.h>
#include <hip/hip_bf16.h>

#define DIMC 768
#define NH 12
#define HD 64
#define BB 4
#define NN 1024
#define BHT 48          // BB*NH
#define QKVC 2304       // 3*DIM

typedef unsigned short u16;
typedef __attribute__((ext_vector_type(4))) unsigned short u16x4;
typedef __attribute__((ext_vector_type(8))) unsigned short u16x8;
typedef __attribute__((ext_vector_type(8))) short s16x8;
typedef __attribute__((ext_vector_type(4))) float f32x4;

// async global->LDS, 16B per lane; lds base must be wave-uniform.
#define GLD16(g, l) __builtin_amdgcn_global_load_lds( \
    (__attribute__((address_space(1))) void*)(g),     \
    (__attribute__((address_space(3))) void*)(l), 16, 0, 0)

__device__ __forceinline__ u16 f2bf(float f) {
    unsigned u = __float_as_uint(f);
    return (u16)((u + 0x7FFF + ((u >> 16) & 1)) >> 16);   // RNE
}
__device__ __forceinline__ float bf2f(u16 v) {
    return __uint_as_float(((unsigned)v) << 16);
}
struct bfp { u16 h, l; };
__device__ __forceinline__ bfp splitf(float f) {
    bfp r;
    r.h = f2bf(f);
    r.l = f2bf(f - bf2f(r.h));      // exact residual, bf16-rounded
    return r;
}

// Bijective XCD swizzle (m204 form): valid when nwg % 8 == 0 (all our grids).
__device__ __forceinline__ int swz_linear() {
    const int nwg = gridDim.x * gridDim.y * gridDim.z;
    const int L = blockIdx.x + gridDim.x * (blockIdx.y + gridDim.y * blockIdx.z);
    return (L & 7) * (nwg >> 3) + (L >> 3);
}

// ---------------------------------------------------------------------------
// Elementwise split: src fp32 -> (hi, lo) bf16. n multiple of 4.
// ---------------------------------------------------------------------------
__global__ __launch_bounds__(256) void split_f2b(
    const float* __restrict__ src, u16* __restrict__ hi, u16* __restrict__ lo,
    int n4)
{
    int idx = blockIdx.x * 256 + threadIdx.x;
    if (idx >= n4) return;
    float4 v = *(const float4*)&src[idx * 4];
    u16x4 h, l;
    bfp s;
    s = splitf(v.x); h[0] = s.h; l[0] = s.l;
    s = splitf(v.y); h[1] = s.h; l[1] = s.l;
    s = splitf(v.z); h[2] = s.h; l[2] = s.l;
    s = splitf(v.w); h[3] = s.h; l[3] = s.l;
    *(u16x4*)&hi[idx * 4] = h;
    *(u16x4*)&lo[idx * 4] = l;
}

// ---------------------------------------------------------------------------
// Generic split-bf16 GEMM: C = A @ B^T + bias (3-term MFMA). Used for proj.
// ---------------------------------------------------------------------------
__global__ __launch_bounds__(256, 3) void gemm3_mfma(
    int Mrows, int Nout, int K,
    const u16* __restrict__ Ahp, const u16* __restrict__ Alp,
    const u16* __restrict__ Bhp, const u16* __restrict__ Blp,
    const float* __restrict__ bias, float* __restrict__ C)
{
    __shared__ alignas(16) u16 sAh[128 * 32], sAl[128 * 32], sBh[128 * 32], sBl[128 * 32];
    const int tid = threadIdx.x;
    const int W = swz_linear();
    const int j0 = (W % gridDim.x) * 128, i0 = (W / gridDim.x) * 128;
    const int w = tid >> 6, l = tid & 63;
    const int wr = w >> 1, wc = w & 1;
    const int l15 = l & 15, kb4 = l >> 4;
    const int lrow = l >> 2, lch = (l & 3) * 8;

    f32x4 acc[4][4];
    const f32x4 zero = {0.f, 0.f, 0.f, 0.f};
#pragma unroll
    for (int a = 0; a < 4; ++a)
#pragma unroll
        for (int b = 0; b < 4; ++b) acc[a][b] = zero;

    for (int k0 = 0; k0 < K; k0 += 32) {
#pragma unroll
        for (int t = 0; t < 2; ++t) {
            const int r = w * 32 + t * 16;
            const size_t ar = (size_t)(i0 + r + lrow) * K + k0 + lch;
            const size_t br = (size_t)(j0 + r + lrow) * K + k0 + lch;
            GLD16(&Ahp[ar], &sAh[r * 32]);
            GLD16(&Alp[ar], &sAl[r * 32]);
            GLD16(&Bhp[br], &sBh[r * 32]);
            GLD16(&Blp[br], &sBl[r * 32]);
        }
        __syncthreads();

        s16x8 ah[4], al[4], bh[4], bl[4];
#pragma unroll
        for (int f = 0; f < 4; ++f) {
            const int ao = (wr * 64 + f * 16 + l15) * 32 + kb4 * 8;
            const int bo = (wc * 64 + f * 16 + l15) * 32 + kb4 * 8;
            ah[f] = *(const s16x8*)&sAh[ao];
            al[f] = *(const s16x8*)&sAl[ao];
            bh[f] = *(const s16x8*)&sBh[bo];
            bl[f] = *(const s16x8*)&sBl[bo];
        }
#pragma unroll
        for (int fr = 0; fr < 4; ++fr)
#pragma unroll
            for (int fc = 0; fc < 4; ++fc) {
                acc[fr][fc] = __builtin_amdgcn_mfma_f32_16x16x32_bf16(
                    ah[fr], bh[fc], acc[fr][fc], 0, 0, 0);
                acc[fr][fc] = __builtin_amdgcn_mfma_f32_16x16x32_bf16(
                    ah[fr], bl[fc], acc[fr][fc], 0, 0, 0);
                acc[fr][fc] = __builtin_amdgcn_mfma_f32_16x16x32_bf16(
                    al[fr], bh[fc], acc[fr][fc], 0, 0, 0);
            }
        __syncthreads();
    }

#pragma unroll
    for (int fr = 0; fr < 4; ++fr)
#pragma unroll
        for (int r = 0; r < 4; ++r) {
            const int gi = i0 + wr * 64 + fr * 16 + kb4 * 4 + r;
#pragma unroll
            for (int fc = 0; fc < 4; ++fc) {
                const int gj = j0 + wc * 64 + fc * 16 + l15;
                C[(size_t)gi * Nout + gj] = acc[fr][fc][r] + bias[gj];
            }
        }
}

// ---------------------------------------------------------------------------
// qkv fused GEMM: qkv = x @ W^T + b, epilogue writes q/k (split, q scaled
// 0.125) in (bh,n,64) layout and v^T (split) in (bh,64,n) layout directly.
// ---------------------------------------------------------------------------
__global__ __launch_bounds__(256, 3) void qkv_fused_mfma(
    const u16* __restrict__ Ahp, const u16* __restrict__ Alp,
    const u16* __restrict__ Bhp, const u16* __restrict__ Blp,
    const float* __restrict__ bias,
    u16* __restrict__ qh, u16* __restrict__ ql,
    u16* __restrict__ kh, u16* __restrict__ kl,
    u16* __restrict__ vth, u16* __restrict__ vtl)
{
    __shared__ alignas(16) u16 sAh[128 * 32], sAl[128 * 32], sBh[128 * 32], sBl[128 * 32];
    const int tid = threadIdx.x;
    const int W = swz_linear();
    const int j0 = (W % gridDim.x) * 128, i0 = (W / gridDim.x) * 128;
    const int w = tid >> 6, l = tid & 63;
    const int wr = w >> 1, wc = w & 1;
    const int l15 = l & 15, kb4 = l >> 4;
    const int lrow = l >> 2, lch = (l & 3) * 8;
    const int K = DIMC;

    f32x4 acc[4][4];
    const f32x4 zero = {0.f, 0.f, 0.f, 0.f};
#pragma unroll
    for (int a = 0; a < 4; ++a)
#pragma unroll
        for (int b = 0; b < 4; ++b) acc[a][b] = zero;

    for (int k0 = 0; k0 < K; k0 += 32) {
#pragma unroll
        for (int t = 0; t < 2; ++t) {
            const int r = w * 32 + t * 16;
            const size_t ar = (size_t)(i0 + r + lrow) * K + k0 + lch;
            const size_t br = (size_t)(j0 + r + lrow) * K + k0 + lch;
            GLD16(&Ahp[ar], &sAh[r * 32]);
            GLD16(&Alp[ar], &sAl[r * 32]);
            GLD16(&Bhp[br], &sBh[r * 32]);
            GLD16(&Blp[br], &sBl[r * 32]);
        }
        __syncthreads();

        s16x8 ah[4], al[4], bh[4], bl[4];
#pragma unroll
        for (int f = 0; f < 4; ++f) {
            const int ao = (wr * 64 + f * 16 + l15) * 32 + kb4 * 8;
            const int bo = (wc * 64 + f * 16 + l15) * 32 + kb4 * 8;
            ah[f] = *(const s16x8*)&sAh[ao];
            al[f] = *(const s16x8*)&sAl[ao];
            bh[f] = *(const s16x8*)&sBh[bo];
            bl[f] = *(const s16x8*)&sBl[bo];
        }
#pragma unroll
        for (int fr = 0; fr < 4; ++fr)
#pragma unroll
            for (int fc = 0; fc < 4; ++fc) {
                acc[fr][fc] = __builtin_amdgcn_mfma_f32_16x16x32_bf16(
                    ah[fr], bh[fc], acc[fr][fc], 0, 0, 0);
                acc[fr][fc] = __builtin_amdgcn_mfma_f32_16x16x32_bf16(
                    ah[fr], bl[fc], acc[fr][fc], 0, 0, 0);
                acc[fr][fc] = __builtin_amdgcn_mfma_f32_16x16x32_bf16(
                    al[fr], bh[fc], acc[fr][fc], 0, 0, 0);
            }
        __syncthreads();
    }

    const int part = j0 / DIMC;               // 0=q, 1=k, 2=v (block-uniform)
    const int hbase = (j0 % DIMC) >> 6;
    const int h = hbase + wc;

#pragma unroll
    for (int fr = 0; fr < 4; ++fr) {
        const int rowbase = i0 + wr * 64 + fr * 16 + kb4 * 4;
        const int b = rowbase >> 10;
        const int n0 = rowbase & 1023;
        const int bh = b * NH + h;
#pragma unroll
        for (int fc = 0; fc < 4; ++fc) {
            const int gj = j0 + wc * 64 + fc * 16 + l15;
            const float bv = bias[gj];
            const int d = fc * 16 + l15;
            if (part == 0) {
#pragma unroll
                for (int r = 0; r < 4; ++r) {
                    bfp s = splitf((acc[fr][fc][r] + bv) * 0.125f);
                    const size_t o = ((size_t)bh * NN + n0 + r) * HD + d;
                    qh[o] = s.h; ql[o] = s.l;
                }
            } else if (part == 1) {
#pragma unroll
                for (int r = 0; r < 4; ++r) {
                    bfp s = splitf(acc[fr][fc][r] + bv);
                    const size_t o = ((size_t)bh * NN + n0 + r) * HD + d;
                    kh[o] = s.h; kl[o] = s.l;
                }
            } else {
                u16x4 hv, lv;
#pragma unroll
                for (int r = 0; r < 4; ++r) {
                    bfp s = splitf(acc[fr][fc][r] + bv);
                    hv[r] = s.h; lv[r] = s.l;
                }
                const size_t o = ((size_t)bh * HD + d) * NN + n0;
                *(u16x4*)&vth[o] = hv;
                *(u16x4*)&vtl[o] = lv;
            }
        }
    }
}

// ---------------------------------------------------------------------------
// qk_mfma: S = (q*0.125) @ k^T per head, split 3-term. K=64.
// ---------------------------------------------------------------------------
__global__ __launch_bounds__(256, 4) void qk_mfma(
    const u16* __restrict__ qh, const u16* __restrict__ ql,
    const u16* __restrict__ kh, const u16* __restrict__ kl,
    float* __restrict__ Sb, int h0)
{
    __shared__ alignas(16) u16 sAh[128 * 32], sAl[128 * 32], sBh[128 * 32], sBl[128 * 32];
    const int tid = threadIdx.x;
    const int W = swz_linear();
    const int bhl = W >> 6;
    const int ib = W & 63;
    const int j0 = (ib & 7) * 128, i0 = (ib >> 3) * 128;
    const int bh = h0 + bhl;
    const int w = tid >> 6, l = tid & 63;
    const int wr = w >> 1, wc = w & 1;
    const int l15 = l & 15, kb4 = l >> 4;
    const int lrow = l >> 2, lch = (l & 3) * 8;

    f32x4 acc[4][4];
    const f32x4 zero = {0.f, 0.f, 0.f, 0.f};
#pragma unroll
    for (int a = 0; a < 4; ++a)
#pragma unroll
        for (int b = 0; b < 4; ++b) acc[a][b] = zero;

    for (int k0 = 0; k0 < HD; k0 += 32) {
#pragma unroll
        for (int t = 0; t < 2; ++t) {
            const int r = w * 32 + t * 16;
            const size_t ar = ((size_t)bh * NN + i0 + r + lrow) * HD + k0 + lch;
            const size_t br = ((size_t)bh * NN + j0 + r + lrow) * HD + k0 + lch;
            GLD16(&qh[ar], &sAh[r * 32]);
            GLD16(&ql[ar], &sAl[r * 32]);
            GLD16(&kh[br], &sBh[r * 32]);
            GLD16(&kl[br], &sBl[r * 32]);
        }
        __syncthreads();

        s16x8 ah[4], al[4], bh[4], bl[4];
#pragma unroll
        for (int f = 0; f < 4; ++f) {
            const int ao = (wr * 64 + f * 16 + l15) * 32 + kb4 * 8;
            const int bo = (wc * 64 + f * 16 + l15) * 32 + kb4 * 8;
            ah[f] = *(const s16x8*)&sAh[ao];
            al[f] = *(const s16x8*)&sAl[ao];
            bh[f] = *(const s16x8*)&sBh[bo];
            bl[f] = *(const s16x8*)&sBl[bo];
        }
#pragma unroll
        for (int fr = 0; fr < 4; ++fr)
#pragma unroll
            for (int fc = 0; fc < 4; ++fc) {
                acc[fr][fc] = __builtin_amdgcn_mfma_f32_16x16x32_bf16(
                    ah[fr], bh[fc], acc[fr][fc], 0, 0, 0);
                acc[fr][fc] = __builtin_amdgcn_mfma_f32_16x16x32_bf16(
                    ah[fr], bl[fc], acc[fr][fc], 0, 0, 0);
                acc[fr][fc] = __builtin_amdgcn_mfma_f32_16x16x32_bf16(
                    al[fr], bh[fc], acc[fr][fc], 0, 0, 0);
            }
        __syncthreads();
    }

    float* Sh = Sb + (size_t)bhl * NN * NN;
#pragma unroll
    for (int fr = 0; fr < 4; ++fr)
#pragma unroll
        for (int r = 0; r < 4; ++r) {
            const int gi = i0 + wr * 64 + fr * 16 + kb4 * 4 + r;
#pragma unroll
            for (int fc = 0; fc < 4; ++fc) {
                const int gj = j0 + wc * 64 + fc * 16 + l15;
                Sh[(size_t)gi * NN + gj] = acc[fr][fc][r];
            }
        }
}

// ---------------------------------------------------------------------------
// wave-softmax: 4 rows/block, one wave per row, no LDS/barriers.
// ---------------------------------------------------------------------------
__global__ __launch_bounds__(256) void softmax_w(
    const float* __restrict__ Sb, u16* __restrict__ Abf)
{
    const int w = threadIdx.x >> 6, l = threadIdx.x & 63;
    const int row = blockIdx.x * 4 + w;
    const float* p = Sb + (size_t)row * NN;
    u16* q = Abf + (size_t)row * NN;

    float4 v[4];
    float m = -1e30f;
#pragma unroll
    for (int c = 0; c < 4; ++c) {
        v[c] = *(const float4*)&p[c * 256 + l * 4];
        m = fmaxf(m, fmaxf(fmaxf(v[c].x, v[c].y), fmaxf(v[c].z, v[c].w)));
    }
#pragma unroll
    for (int off = 32; off >= 1; off >>= 1) m = fmaxf(m, __shfl_xor(m, off));

    float s = 0.f;
#pragma unroll
    for (int c = 0; c < 4; ++c) {
        v[c].x = expf(v[c].x - m); v[c].y = expf(v[c].y - m);
        v[c].z = expf(v[c].z - m); v[c].w = expf(v[c].w - m);
        s += v[c].x + v[c].y + v[c].z + v[c].w;
    }
#pragma unroll
    for (int off = 32; off >= 1; off >>= 1) s += __shfl_xor(s, off);

    const float inv = 1.0f / s;
#pragma unroll
    for (int c = 0; c < 4; ++c) {
        u16x4 o;
        o[0] = f2bf(v[c].x * inv); o[1] = f2bf(v[c].y * inv);
        o[2] = f2bf(v[c].z * inv); o[3] = f2bf(v[c].w * inv);
        *(u16x4*)&q[c * 256 + l * 4] = o;
    }
}

// ---------------------------------------------------------------------------
// mpow: acc = A @ B' where B' = c2*A^T + c1*I is built IN-LOOP during the
// B-transpose staging (no separate transpose pass, no epilogue A-read).
// M = relu(acc + del*I). BK=64, 128B LDS rows, k-chunk XOR swizzle
// (phys chunk = logical ^ (row&7)) on GLD16-source / B-write / frag-read.
// ---------------------------------------------------------------------------
__global__ __launch_bounds__(256, 4) void mpow_mfma(
    const u16* __restrict__ Abf, u16* __restrict__ Mb,
    const float* __restrict__ lamb, const float* __restrict__ gamma,
    const float* __restrict__ delta, int h0)
{
    __shared__ alignas(16) u16 sA[128 * 64], sB[128 * 64];
    const int tid = threadIdx.x;
    const int W = swz_linear();
    const int bz = W >> 6;
    const int ib = W & 63;
    const int j0 = (ib & 7) * 128, i0 = (ib >> 3) * 128;
    const int h = (h0 + bz) % NH;
    const u16* Ah = Abf + (size_t)bz * NN * NN;
    const float lam = lamb[h];
    const float c1 = gamma[h] - 6.0f * lam;
    const float c2 = 7.0f * lam;

    const int w = tid >> 6, l = tid & 63;
    const int wr = w >> 1, wc = w & 1;
    const int l15 = l & 15, kb4 = l >> 4;
    const int lr8 = l >> 3;                 // row-in-8-group for GLD16
    const int srck = ((l & 7) ^ lr8) * 8;   // pre-swizzled source k offset
    const int kr = tid & 31;
    const int jc = (tid >> 5) * 16;

    f32x4 acc[4][4];
    const f32x4 zero = {0.f, 0.f, 0.f, 0.f};
#pragma unroll
    for (int a = 0; a < 4; ++a)
#pragma unroll
        for (int b = 0; b < 4; ++b) acc[a][b] = zero;

    for (int k0 = 0; k0 < NN; k0 += 64) {
        // A-side: 4 GLD16 per thread, linear LDS dest, pre-swizzled source
#pragma unroll
        for (int t = 0; t < 4; ++t) {
            const int r = w * 32 + t * 8;
            GLD16(&Ah[(size_t)(i0 + r + lr8) * NN + k0 + srck], &sA[r * 64]);
        }
        // B-side: read A's k-rows coalesced, write transposed + swizzled,
        // applying B' = c2*A^T + c1*I on the fly.
#pragma unroll
        for (int kk2 = 0; kk2 < 64; kk2 += 32) {
            const int kloc = kk2 + kr;
            const int gk = k0 + kloc;
            const u16* arow = &Ah[(size_t)gk * NN + j0 + jc];
            u16x8 b0 = *(const u16x8*)arow;
            u16x8 b1 = *(const u16x8*)(arow + 8);
            const int kc = kloc >> 3, ke = kloc & 7;
#pragma unroll
            for (int e = 0; e < 8; ++e) {
                const int j1 = jc + e, j2 = jc + 8 + e;
                float v1 = c2 * bf2f(b0[e]) + ((j0 + j1) == gk ? c1 : 0.f);
                float v2 = c2 * bf2f(b1[e]) + ((j0 + j2) == gk ? c1 : 0.f);
                sB[j1 * 64 + ((kc ^ (j1 & 7)) * 8) + ke] = f2bf(v1);
                sB[j2 * 64 + ((kc ^ (j2 & 7)) * 8) + ke] = f2bf(v2);
            }
        }
        __syncthreads();

#pragma unroll
        for (int kk = 0; kk < 64; kk += 32) {
            const int ck = kk >> 3;
            s16x8 af[4], bf[4];
#pragma unroll
            for (int f = 0; f < 4; ++f) {
                const int ar_ = wr * 64 + f * 16 + l15;
                const int br_ = wc * 64 + f * 16 + l15;
                af[f] = *(const s16x8*)&sA[ar_ * 64 + (((ck + kb4) ^ (ar_ & 7)) * 8)];
                bf[f] = *(const s16x8*)&sB[br_ * 64 + (((ck + kb4) ^ (br_ & 7)) * 8)];
            }
#pragma unroll
            for (int fr = 0; fr < 4; ++fr)
#pragma unroll
                for (int fc = 0; fc < 4; ++fc)
                    acc[fr][fc] = __builtin_amdgcn_mfma_f32_16x16x32_bf16(
                        af[fr], bf[fc], acc[fr][fc], 0, 0, 0);
        }
        __syncthreads();
    }

    const float del = delta[h];
    u16* Mh = Mb + (size_t)bz * NN * NN;

#pragma unroll
    for (int fr = 0; fr < 4; ++fr)
#pragma unroll
        for (int r = 0; r < 4; ++r) {
            const int gi = i0 + wr * 64 + fr * 16 + kb4 * 4 + r;
#pragma unroll
            for (int fc = 0; fc < 4; ++fc) {
                const int gj = j0 + wc * 64 + fc * 16 + l15;
                float m = acc[fr][fc][r] + (gi == gj ? del : 0.f);
                m = fmaxf(m, 0.f);
                Mh[(size_t)gi * NN + gj] = f2bf(m);
            }
        }
}

// ---------------------------------------------------------------------------
// pv: ao = (M @ V) / rowsum(M). V as v^T hi/lo (2-term split); rowsum via
// ones-MFMA. 64-row tiles -> grid (16, CH).
// ---------------------------------------------------------------------------
__global__ __launch_bounds__(256, 4) void pv_mfma(
    const u16* __restrict__ Mb,
    const u16* __restrict__ vth, const u16* __restrict__ vtl,
    u16* __restrict__ aoh, u16* __restrict__ aol, int h0)
{
    __shared__ alignas(16) u16 sM[64 * 32], sVh[64 * 32], sVl[64 * 32];
    const int tid = threadIdx.x;
    const int W = swz_linear();
    const int bhl = W >> 4;
    const int i0 = (W & 15) * 64;
    const int bh = h0 + bhl;
    const int b = bh / NH, h = bh % NH;
    const u16* Mh = Mb + (size_t)bhl * NN * NN;
    const u16* vhb = vth + (size_t)bh * HD * NN;
    const u16* vlb = vtl + (size_t)bh * HD * NN;

    const int w = tid >> 6, l = tid & 63;
    const int l15 = l & 15, kb4 = l >> 4;
    const int lrow = l >> 2, lch = (l & 3) * 8;

    f32x4 acc[4], accs;
    const f32x4 zero = {0.f, 0.f, 0.f, 0.f};
#pragma unroll
    for (int c = 0; c < 4; ++c) acc[c] = zero;
    accs = zero;
    s16x8 ones;
#pragma unroll
    for (int e = 0; e < 8; ++e) ones[e] = (short)0x3F80;   // bf16 1.0

    for (int k0 = 0; k0 < NN; k0 += 32) {
        {
            const int r = w * 16;                  // M rows: 4 waves x 16 = 64
            GLD16(&Mh[(size_t)(i0 + r + lrow) * NN + k0 + lch], &sM[r * 32]);
            const size_t vr = (size_t)(r + lrow) * NN + k0 + lch;
            GLD16(&vhb[vr], &sVh[r * 32]);
            GLD16(&vlb[vr], &sVl[r * 32]);
        }
        __syncthreads();

        s16x8 af, bh[4], bl[4];
        af = *(const s16x8*)&sM[(w * 16 + l15) * 32 + kb4 * 8];
#pragma unroll
        for (int f = 0; f < 4; ++f) {
            bh[f] = *(const s16x8*)&sVh[(f * 16 + l15) * 32 + kb4 * 8];
            bl[f] = *(const s16x8*)&sVl[(f * 16 + l15) * 32 + kb4 * 8];
        }
#pragma unroll
        for (int fc = 0; fc < 4; ++fc) {
            acc[fc] = __builtin_amdgcn_mfma_f32_16x16x32_bf16(
                af, bh[fc], acc[fc], 0, 0, 0);
            acc[fc] = __builtin_amdgcn_mfma_f32_16x16x32_bf16(
                af, bl[fc], acc[fc], 0, 0, 0);
        }
        accs = __builtin_amdgcn_mfma_f32_16x16x32_bf16(af, ones, accs, 0, 0, 0);
        __syncthreads();
    }

#pragma unroll
    for (int r = 0; r < 4; ++r) {
        const int gi = i0 + w * 16 + kb4 * 4 + r;
        const float inv = 1.0f / (accs[r] + 1e-9f);
        const size_t ob = (size_t)(b * NN + gi) * DIMC + h * HD;
#pragma unroll
        for (int fc = 0; fc < 4; ++fc) {
            const int gd = fc * 16 + l15;
            bfp s = splitf(acc[fc][r] * inv);
            aoh[ob + gd] = s.h;
            aol[ob + gd] = s.l;
        }
    }
}

// ---------------------------------------------------------------------------
extern "C" void kernel_launch(void* const* d_in, const int* in_sizes, int n_in,
                              void* d_out, int out_size, void* d_ws, size_t ws_size,
                              hipStream_t stream)
{
    const float* x      = (const float*)d_in[0];
    const float* qkv_w  = (const float*)d_in[1];
    const float* qkv_b  = (const float*)d_in[2];
    const float* proj_w = (const float*)d_in[3];
    const float* proj_b = (const float*)d_in[4];
    const float* lamb   = (const float*)d_in[5];
    const float* gamma  = (const float*)d_in[6];
    const float* delta  = (const float*)d_in[7];

    char* p = (char*)d_ws;
    u16* xh  = (u16*)p;                     p += (size_t)4096 * DIMC * 2;
    u16* xl  = (u16*)p;                     p += (size_t)4096 * DIMC * 2;
    u16* wh  = (u16*)p;                     p += (size_t)QKVC * DIMC * 2;
    u16* wl  = (u16*)p;                     p += (size_t)QKVC * DIMC * 2;
    u16* pwh = (u16*)p;                     p += (size_t)DIMC * DIMC * 2;
    u16* pwl = (u16*)p;                     p += (size_t)DIMC * DIMC * 2;
    u16* qh  = (u16*)p;                     p += (size_t)BHT * NN * HD * 2;
    u16* ql  = (u16*)p;                     p += (size_t)BHT * NN * HD * 2;
    u16* kh  = (u16*)p;                     p += (size_t)BHT * NN * HD * 2;
    u16* kl  = (u16*)p;                     p += (size_t)BHT * NN * HD * 2;
    u16* vth = (u16*)p;                     p += (size_t)BHT * HD * NN * 2;
    u16* vtl = (u16*)p;                     p += (size_t)BHT * HD * NN * 2;
    u16* aoh = (u16*)p;                     p += (size_t)4096 * DIMC * 2;
    u16* aol = (u16*)p;                     p += (size_t)4096 * DIMC * 2;
    const size_t fixed = (size_t)(p - (char*)d_ws);

    // per-head: S fp32 4MB (M bf16 aliases into it) + A bf16 2MB
    const size_t perh = (size_t)NN * NN * 4 + (size_t)NN * NN * 2;
    static const int choices[] = {48, 24, 16, 12, 8, 6, 4, 3, 2, 1};
    int CH = 1;
    for (int ci = 0; ci < 10; ++ci) {
        int c = choices[ci];
        if (fixed + (size_t)c * perh <= ws_size) { CH = c; break; }
    }

    float* Sb = (float*)p;                  p += (size_t)CH * NN * NN * 4;
    u16* Abf  = (u16*)p;                    p += (size_t)CH * NN * NN * 2;
    u16* Mb   = (u16*)Sb;                   // alias: S dead after softmax

    // 0) splits of inputs
    split_f2b<<<dim3((4096 * DIMC / 4 + 255) / 256), 256, 0, stream>>>(x, xh, xl, 4096 * DIMC / 4);
    split_f2b<<<dim3((QKVC * DIMC / 4 + 255) / 256), 256, 0, stream>>>(qkv_w, wh, wl, QKVC * DIMC / 4);
    split_f2b<<<dim3((DIMC * DIMC / 4 + 255) / 256), 256, 0, stream>>>(proj_w, pwh, pwl, DIMC * DIMC / 4);

    // 1) qkv GEMM fused: writes qh/ql/kh/kl (bh,n,64) and vth/vtl (bh,64,n)
    qkv_fused_mfma<<<dim3(QKVC / 128, 4096 / 128), 256, 0, stream>>>(
        xh, xl, wh, wl, qkv_b, qh, ql, kh, kl, vth, vtl);

    // 2..5) per chunk of heads
    for (int h0 = 0; h0 < BHT; h0 += CH) {
        qk_mfma<<<dim3(8, 8, CH), 256, 0, stream>>>(qh, ql, kh, kl, Sb, h0);
        softmax_w<<<dim3(CH * NN / 4), 256, 0, stream>>>(Sb, Abf);
        mpow_mfma<<<dim3(8, 8, CH), 256, 0, stream>>>(
            Abf, Mb, lamb, gamma, delta, h0);
        pv_mfma<<<dim3(16, CH), 256, 0, stream>>>(Mb, vth, vtl, aoh, aol, h0);
    }

    // 6) final = ao @ proj_w^T + proj_b
    gemm3_mfma<<<dim3(DIMC / 128, 4096 / 128), 256, 0, stream>>>(
        4096, DIMC, DIMC, aoh, aol, pwh, pwl, proj_b, (float*)d_out);
}

// Round 19
// 401.047 us; speedup vs baseline: 1.6489x; 1.6489x over previous
//
#include <hip/hip_runtime.h>
#include <hip/hip_bf16.h>

#define DIMC 768
#define NH 12
#define HD 64
#define BB 4
#define NN 1024
#define BHT 48          // BB*NH
#define QKVC 2304       // 3*DIM

typedef unsigned short u16;
typedef __attribute__((ext_vector_type(4))) unsigned short u16x4;
typedef __attribute__((ext_vector_type(8))) unsigned short u16x8;
typedef __attribute__((ext_vector_type(8))) short s16x8;
typedef __attribute__((ext_vector_type(4))) float f32x4;

// async global->LDS, 16B per lane; lds base must be wave-uniform.
#define GLD16(g, l) __builtin_amdgcn_global_load_lds( \
    (__attribute__((address_space(1))) void*)(g),     \
    (__attribute__((address_space(3))) void*)(l), 16, 0, 0)

__device__ __forceinline__ u16 f2bf(float f) {
    unsigned u = __float_as_uint(f);
    return (u16)((u + 0x7FFF + ((u >> 16) & 1)) >> 16);   // RNE
}
__device__ __forceinline__ float bf2f(u16 v) {
    return __uint_as_float(((unsigned)v) << 16);
}
struct bfp { u16 h, l; };
__device__ __forceinline__ bfp splitf(float f) {
    bfp r;
    r.h = f2bf(f);
    r.l = f2bf(f - bf2f(r.h));      // exact residual, bf16-rounded
    return r;
}

// Bijective XCD swizzle (m204 form): valid when nwg % 8 == 0 (all our grids).
__device__ __forceinline__ int swz_linear() {
    const int nwg = gridDim.x * gridDim.y * gridDim.z;
    const int L = blockIdx.x + gridDim.x * (blockIdx.y + gridDim.y * blockIdx.z);
    return (L & 7) * (nwg >> 3) + (L >> 3);
}

// ---------------------------------------------------------------------------
// Elementwise split: src fp32 -> (hi, lo) bf16. n multiple of 4.
// ---------------------------------------------------------------------------
__global__ __launch_bounds__(256) void split_f2b(
    const float* __restrict__ src, u16* __restrict__ hi, u16* __restrict__ lo,
    int n4)
{
    int idx = blockIdx.x * 256 + threadIdx.x;
    if (idx >= n4) return;
    float4 v = *(const float4*)&src[idx * 4];
    u16x4 h, l;
    bfp s;
    s = splitf(v.x); h[0] = s.h; l[0] = s.l;
    s = splitf(v.y); h[1] = s.h; l[1] = s.l;
    s = splitf(v.z); h[2] = s.h; l[2] = s.l;
    s = splitf(v.w); h[3] = s.h; l[3] = s.l;
    *(u16x4*)&hi[idx * 4] = h;
    *(u16x4*)&lo[idx * 4] = l;
}

// ---------------------------------------------------------------------------
// Generic split-bf16 GEMM: C = A @ B^T + bias (3-term MFMA). Used for proj.
// ---------------------------------------------------------------------------
__global__ __launch_bounds__(256, 3) void gemm3_mfma(
    int Mrows, int Nout, int K,
    const u16* __restrict__ Ahp, const u16* __restrict__ Alp,
    const u16* __restrict__ Bhp, const u16* __restrict__ Blp,
    const float* __restrict__ bias, float* __restrict__ C)
{
    __shared__ alignas(16) u16 sAh[128 * 32], sAl[128 * 32], sBh[128 * 32], sBl[128 * 32];
    const int tid = threadIdx.x;
    const int W = swz_linear();
    const int j0 = (W % gridDim.x) * 128, i0 = (W / gridDim.x) * 128;
    const int w = tid >> 6, l = tid & 63;
    const int wr = w >> 1, wc = w & 1;
    const int l15 = l & 15, kb4 = l >> 4;
    const int lrow = l >> 2, lch = (l & 3) * 8;

    f32x4 acc[4][4];
    const f32x4 zero = {0.f, 0.f, 0.f, 0.f};
#pragma unroll
    for (int a = 0; a < 4; ++a)
#pragma unroll
        for (int b = 0; b < 4; ++b) acc[a][b] = zero;

    for (int k0 = 0; k0 < K; k0 += 32) {
#pragma unroll
        for (int t = 0; t < 2; ++t) {
            const int r = w * 32 + t * 16;
            const size_t ar = (size_t)(i0 + r + lrow) * K + k0 + lch;
            const size_t br = (size_t)(j0 + r + lrow) * K + k0 + lch;
            GLD16(&Ahp[ar], &sAh[r * 32]);
            GLD16(&Alp[ar], &sAl[r * 32]);
            GLD16(&Bhp[br], &sBh[r * 32]);
            GLD16(&Blp[br], &sBl[r * 32]);
        }
        __syncthreads();

        s16x8 ah[4], al[4], bh[4], bl[4];
#pragma unroll
        for (int f = 0; f < 4; ++f) {
            const int ao = (wr * 64 + f * 16 + l15) * 32 + kb4 * 8;
            const int bo = (wc * 64 + f * 16 + l15) * 32 + kb4 * 8;
            ah[f] = *(const s16x8*)&sAh[ao];
            al[f] = *(const s16x8*)&sAl[ao];
            bh[f] = *(const s16x8*)&sBh[bo];
            bl[f] = *(const s16x8*)&sBl[bo];
        }
#pragma unroll
        for (int fr = 0; fr < 4; ++fr)
#pragma unroll
            for (int fc = 0; fc < 4; ++fc) {
                acc[fr][fc] = __builtin_amdgcn_mfma_f32_16x16x32_bf16(
                    ah[fr], bh[fc], acc[fr][fc], 0, 0, 0);
                acc[fr][fc] = __builtin_amdgcn_mfma_f32_16x16x32_bf16(
                    ah[fr], bl[fc], acc[fr][fc], 0, 0, 0);
                acc[fr][fc] = __builtin_amdgcn_mfma_f32_16x16x32_bf16(
                    al[fr], bh[fc], acc[fr][fc], 0, 0, 0);
            }
        __syncthreads();
    }

#pragma unroll
    for (int fr = 0; fr < 4; ++fr)
#pragma unroll
        for (int r = 0; r < 4; ++r) {
            const int gi = i0 + wr * 64 + fr * 16 + kb4 * 4 + r;
#pragma unroll
            for (int fc = 0; fc < 4; ++fc) {
                const int gj = j0 + wc * 64 + fc * 16 + l15;
                C[(size_t)gi * Nout + gj] = acc[fr][fc][r] + bias[gj];
            }
        }
}

// ---------------------------------------------------------------------------
// qkv fused GEMM: qkv = x @ W^T + b, epilogue writes q/k (split, q scaled
// 0.125) in (bh,n,64) layout and v^T (split) in (bh,64,n) layout directly.
// ---------------------------------------------------------------------------
__global__ __launch_bounds__(256, 3) void qkv_fused_mfma(
    const u16* __restrict__ Ahp, const u16* __restrict__ Alp,
    const u16* __restrict__ Bhp, const u16* __restrict__ Blp,
    const float* __restrict__ bias,
    u16* __restrict__ qh, u16* __restrict__ ql,
    u16* __restrict__ kh, u16* __restrict__ kl,
    u16* __restrict__ vth, u16* __restrict__ vtl)
{
    __shared__ alignas(16) u16 sAh[128 * 32], sAl[128 * 32], sBh[128 * 32], sBl[128 * 32];
    const int tid = threadIdx.x;
    const int W = swz_linear();
    const int j0 = (W % gridDim.x) * 128, i0 = (W / gridDim.x) * 128;
    const int w = tid >> 6, l = tid & 63;
    const int wr = w >> 1, wc = w & 1;
    const int l15 = l & 15, kb4 = l >> 4;
    const int lrow = l >> 2, lch = (l & 3) * 8;
    const int K = DIMC;

    f32x4 acc[4][4];
    const f32x4 zero = {0.f, 0.f, 0.f, 0.f};
#pragma unroll
    for (int a = 0; a < 4; ++a)
#pragma unroll
        for (int b = 0; b < 4; ++b) acc[a][b] = zero;

    for (int k0 = 0; k0 < K; k0 += 32) {
#pragma unroll
        for (int t = 0; t < 2; ++t) {
            const int r = w * 32 + t * 16;
            const size_t ar = (size_t)(i0 + r + lrow) * K + k0 + lch;
            const size_t br = (size_t)(j0 + r + lrow) * K + k0 + lch;
            GLD16(&Ahp[ar], &sAh[r * 32]);
            GLD16(&Alp[ar], &sAl[r * 32]);
            GLD16(&Bhp[br], &sBh[r * 32]);
            GLD16(&Blp[br], &sBl[r * 32]);
        }
        __syncthreads();

        s16x8 ah[4], al[4], bh[4], bl[4];
#pragma unroll
        for (int f = 0; f < 4; ++f) {
            const int ao = (wr * 64 + f * 16 + l15) * 32 + kb4 * 8;
            const int bo = (wc * 64 + f * 16 + l15) * 32 + kb4 * 8;
            ah[f] = *(const s16x8*)&sAh[ao];
            al[f] = *(const s16x8*)&sAl[ao];
            bh[f] = *(const s16x8*)&sBh[bo];
            bl[f] = *(const s16x8*)&sBl[bo];
        }
#pragma unroll
        for (int fr = 0; fr < 4; ++fr)
#pragma unroll
            for (int fc = 0; fc < 4; ++fc) {
                acc[fr][fc] = __builtin_amdgcn_mfma_f32_16x16x32_bf16(
                    ah[fr], bh[fc], acc[fr][fc], 0, 0, 0);
                acc[fr][fc] = __builtin_amdgcn_mfma_f32_16x16x32_bf16(
                    ah[fr], bl[fc], acc[fr][fc], 0, 0, 0);
                acc[fr][fc] = __builtin_amdgcn_mfma_f32_16x16x32_bf16(
                    al[fr], bh[fc], acc[fr][fc], 0, 0, 0);
            }
        __syncthreads();
    }

    const int part = j0 / DIMC;               // 0=q, 1=k, 2=v (block-uniform)
    const int hbase = (j0 % DIMC) >> 6;
    const int h = hbase + wc;

#pragma unroll
    for (int fr = 0; fr < 4; ++fr) {
        const int rowbase = i0 + wr * 64 + fr * 16 + kb4 * 4;
        const int b = rowbase >> 10;
        const int n0 = rowbase & 1023;
        const int bh = b * NH + h;
#pragma unroll
        for (int fc = 0; fc < 4; ++fc) {
            const int gj = j0 + wc * 64 + fc * 16 + l15;
            const float bv = bias[gj];
            const int d = fc * 16 + l15;
            if (part == 0) {
#pragma unroll
                for (int r = 0; r < 4; ++r) {
                    bfp s = splitf((acc[fr][fc][r] + bv) * 0.125f);
                    const size_t o = ((size_t)bh * NN + n0 + r) * HD + d;
                    qh[o] = s.h; ql[o] = s.l;
                }
            } else if (part == 1) {
#pragma unroll
                for (int r = 0; r < 4; ++r) {
                    bfp s = splitf(acc[fr][fc][r] + bv);
                    const size_t o = ((size_t)bh * NN + n0 + r) * HD + d;
                    kh[o] = s.h; kl[o] = s.l;
                }
            } else {
                u16x4 hv, lv;
#pragma unroll
                for (int r = 0; r < 4; ++r) {
                    bfp s = splitf(acc[fr][fc][r] + bv);
                    hv[r] = s.h; lv[r] = s.l;
                }
                const size_t o = ((size_t)bh * HD + d) * NN + n0;
                *(u16x4*)&vth[o] = hv;
                *(u16x4*)&vtl[o] = lv;
            }
        }
    }
}

// ---------------------------------------------------------------------------
// qk_mfma: S = (q*0.125) @ k^T per head, split 3-term. K=64.
// ---------------------------------------------------------------------------
__global__ __launch_bounds__(256, 4) void qk_mfma(
    const u16* __restrict__ qh, const u16* __restrict__ ql,
    const u16* __restrict__ kh, const u16* __restrict__ kl,
    float* __restrict__ Sb, int h0)
{
    __shared__ alignas(16) u16 sAh[128 * 32], sAl[128 * 32], sBh[128 * 32], sBl[128 * 32];
    const int tid = threadIdx.x;
    const int W = swz_linear();
    const int bhl = W >> 6;
    const int ib = W & 63;
    const int j0 = (ib & 7) * 128, i0 = (ib >> 3) * 128;
    const int bh = h0 + bhl;
    const int w = tid >> 6, l = tid & 63;
    const int wr = w >> 1, wc = w & 1;
    const int l15 = l & 15, kb4 = l >> 4;
    const int lrow = l >> 2, lch = (l & 3) * 8;

    f32x4 acc[4][4];
    const f32x4 zero = {0.f, 0.f, 0.f, 0.f};
#pragma unroll
    for (int a = 0; a < 4; ++a)
#pragma unroll
        for (int b = 0; b < 4; ++b) acc[a][b] = zero;

    for (int k0 = 0; k0 < HD; k0 += 32) {
#pragma unroll
        for (int t = 0; t < 2; ++t) {
            const int r = w * 32 + t * 16;
            const size_t ar = ((size_t)bh * NN + i0 + r + lrow) * HD + k0 + lch;
            const size_t br = ((size_t)bh * NN + j0 + r + lrow) * HD + k0 + lch;
            GLD16(&qh[ar], &sAh[r * 32]);
            GLD16(&ql[ar], &sAl[r * 32]);
            GLD16(&kh[br], &sBh[r * 32]);
            GLD16(&kl[br], &sBl[r * 32]);
        }
        __syncthreads();

        s16x8 ah[4], al[4], bh[4], bl[4];
#pragma unroll
        for (int f = 0; f < 4; ++f) {
            const int ao = (wr * 64 + f * 16 + l15) * 32 + kb4 * 8;
            const int bo = (wc * 64 + f * 16 + l15) * 32 + kb4 * 8;
            ah[f] = *(const s16x8*)&sAh[ao];
            al[f] = *(const s16x8*)&sAl[ao];
            bh[f] = *(const s16x8*)&sBh[bo];
            bl[f] = *(const s16x8*)&sBl[bo];
        }
#pragma unroll
        for (int fr = 0; fr < 4; ++fr)
#pragma unroll
            for (int fc = 0; fc < 4; ++fc) {
                acc[fr][fc] = __builtin_amdgcn_mfma_f32_16x16x32_bf16(
                    ah[fr], bh[fc], acc[fr][fc], 0, 0, 0);
                acc[fr][fc] = __builtin_amdgcn_mfma_f32_16x16x32_bf16(
                    ah[fr], bl[fc], acc[fr][fc], 0, 0, 0);
                acc[fr][fc] = __builtin_amdgcn_mfma_f32_16x16x32_bf16(
                    al[fr], bh[fc], acc[fr][fc], 0, 0, 0);
            }
        __syncthreads();
    }

    float* Sh = Sb + (size_t)bhl * NN * NN;
#pragma unroll
    for (int fr = 0; fr < 4; ++fr)
#pragma unroll
        for (int r = 0; r < 4; ++r) {
            const int gi = i0 + wr * 64 + fr * 16 + kb4 * 4 + r;
#pragma unroll
            for (int fc = 0; fc < 4; ++fc) {
                const int gj = j0 + wc * 64 + fc * 16 + l15;
                Sh[(size_t)gi * NN + gj] = acc[fr][fc][r];
            }
        }
}

// ---------------------------------------------------------------------------
// wave-softmax: 4 rows/block, one wave per row, no LDS/barriers.
// ---------------------------------------------------------------------------
__global__ __launch_bounds__(256) void softmax_w(
    const float* __restrict__ Sb, u16* __restrict__ Abf)
{
    const int w = threadIdx.x >> 6, l = threadIdx.x & 63;
    const int row = blockIdx.x * 4 + w;
    const float* p = Sb + (size_t)row * NN;
    u16* q = Abf + (size_t)row * NN;

    float4 v[4];
    float m = -1e30f;
#pragma unroll
    for (int c = 0; c < 4; ++c) {
        v[c] = *(const float4*)&p[c * 256 + l * 4];
        m = fmaxf(m, fmaxf(fmaxf(v[c].x, v[c].y), fmaxf(v[c].z, v[c].w)));
    }
#pragma unroll
    for (int off = 32; off >= 1; off >>= 1) m = fmaxf(m, __shfl_xor(m, off));

    float s = 0.f;
#pragma unroll
    for (int c = 0; c < 4; ++c) {
        v[c].x = expf(v[c].x - m); v[c].y = expf(v[c].y - m);
        v[c].z = expf(v[c].z - m); v[c].w = expf(v[c].w - m);
        s += v[c].x + v[c].y + v[c].z + v[c].w;
    }
#pragma unroll
    for (int off = 32; off >= 1; off >>= 1) s += __shfl_xor(s, off);

    const float inv = 1.0f / s;
#pragma unroll
    for (int c = 0; c < 4; ++c) {
        u16x4 o;
        o[0] = f2bf(v[c].x * inv); o[1] = f2bf(v[c].y * inv);
        o[2] = f2bf(v[c].z * inv); o[3] = f2bf(v[c].w * inv);
        *(u16x4*)&q[c * 256 + l * 4] = o;
    }
}

// ---------------------------------------------------------------------------
// mpow: P = A@A (bf16 MFMA); M = relu(del*I + c1*A + c2*P) -> bf16.
// BK=64: half the barriers of BK=32 (amortize the 2-phase drain stall).
// 128B LDS rows; swizzle: phys 16B-chunk = logical ^ (row&7), applied on
// GLD16 pre-swizzled global source, B-transpose writes, and frag reads.
// ---------------------------------------------------------------------------
__global__ __launch_bounds__(256, 4) void mpow_mfma(
    const u16* __restrict__ Abf, u16* __restrict__ Mb,
    const float* __restrict__ lamb, const float* __restrict__ gamma,
    const float* __restrict__ delta, int h0)
{
    __shared__ alignas(16) u16 sA[128 * 64], sB[128 * 64];
    const int tid = threadIdx.x;
    const int W = swz_linear();
    const int bz = W >> 6;
    const int ib = W & 63;
    const int j0 = (ib & 7) * 128, i0 = (ib >> 3) * 128;
    const int h = (h0 + bz) % NH;
    const u16* Ah = Abf + (size_t)bz * NN * NN;

    const int w = tid >> 6, l = tid & 63;
    const int wr = w >> 1, wc = w & 1;
    const int l15 = l & 15, kb4 = l >> 4;
    const int lr8 = l >> 3;                 // row-in-8-group for GLD16
    const int srck = ((l & 7) ^ lr8) * 8;   // pre-swizzled source k offset
    const int kr = tid & 31;
    const int jc = (tid >> 5) * 16;

    f32x4 acc[4][4];
    const f32x4 zero = {0.f, 0.f, 0.f, 0.f};
#pragma unroll
    for (int a = 0; a < 4; ++a)
#pragma unroll
        for (int b = 0; b < 4; ++b) acc[a][b] = zero;

    for (int k0 = 0; k0 < NN; k0 += 64) {
        // A-side: 4 GLD16 per thread, 8 rows (128B) per wave-call, linear LDS
#pragma unroll
        for (int t = 0; t < 4; ++t) {
            const int r = w * 32 + t * 8;
            GLD16(&Ah[(size_t)(i0 + r + lr8) * NN + k0 + srck], &sA[r * 64]);
        }
        // B-side: read A's k-rows coalesced, write transposed + swizzled
#pragma unroll
        for (int kk2 = 0; kk2 < 64; kk2 += 32) {
            const int kloc = kk2 + kr;
            const u16* arow = &Ah[(size_t)(k0 + kloc) * NN + j0 + jc];
            u16x8 b0 = *(const u16x8*)arow;
            u16x8 b1 = *(const u16x8*)(arow + 8);
            const int kc = kloc >> 3, ke = kloc & 7;
#pragma unroll
            for (int e = 0; e < 8; ++e) {
                const int j1 = jc + e, j2 = jc + 8 + e;
                sB[j1 * 64 + ((kc ^ (j1 & 7)) * 8) + ke] = b0[e];
                sB[j2 * 64 + ((kc ^ (j2 & 7)) * 8) + ke] = b1[e];
            }
        }
        __syncthreads();

#pragma unroll
        for (int kk = 0; kk < 64; kk += 32) {
            const int ck = kk >> 3;
            s16x8 af[4], bf[4];
#pragma unroll
            for (int f = 0; f < 4; ++f) {
                const int ar_ = wr * 64 + f * 16 + l15;
                const int br_ = wc * 64 + f * 16 + l15;
                af[f] = *(const s16x8*)&sA[ar_ * 64 + (((ck + kb4) ^ (ar_ & 7)) * 8)];
                bf[f] = *(const s16x8*)&sB[br_ * 64 + (((ck + kb4) ^ (br_ & 7)) * 8)];
            }
#pragma unroll
            for (int fr = 0; fr < 4; ++fr)
#pragma unroll
                for (int fc = 0; fc < 4; ++fc)
                    acc[fr][fc] = __builtin_amdgcn_mfma_f32_16x16x32_bf16(
                        af[fr], bf[fc], acc[fr][fc], 0, 0, 0);
        }
        __syncthreads();
    }

    const float lam = lamb[h];
    const float c1 = gamma[h] - 6.0f * lam;
    const float c2 = 7.0f * lam;
    const float del = delta[h];
    u16* Mh = Mb + (size_t)bz * NN * NN;

#pragma unroll
    for (int fr = 0; fr < 4; ++fr)
#pragma unroll
        for (int r = 0; r < 4; ++r) {
            const int gi = i0 + wr * 64 + fr * 16 + kb4 * 4 + r;
#pragma unroll
            for (int fc = 0; fc < 4; ++fc) {
                const int gj = j0 + wc * 64 + fc * 16 + l15;
                const float a = bf2f(Ah[(size_t)gi * NN + gj]);
                float m = c2 * acc[fr][fc][r] + c1 * a + (gi == gj ? del : 0.f);
                m = fmaxf(m, 0.f);
                Mh[(size_t)gi * NN + gj] = f2bf(m);
            }
        }
}

// ---------------------------------------------------------------------------
// pv: ao = (M @ V) / rowsum(M). V as v^T hi/lo (2-term split); rowsum via
// ones-MFMA. 64-row tiles -> grid (16, CH) = 2x blocks for CU coverage.
// ---------------------------------------------------------------------------
__global__ __launch_bounds__(256, 4) void pv_mfma(
    const u16* __restrict__ Mb,
    const u16* __restrict__ vth, const u16* __restrict__ vtl,
    u16* __restrict__ aoh, u16* __restrict__ aol, int h0)
{
    __shared__ alignas(16) u16 sM[64 * 32], sVh[64 * 32], sVl[64 * 32];
    const int tid = threadIdx.x;
    const int W = swz_linear();
    const int bhl = W >> 4;
    const int i0 = (W & 15) * 64;
    const int bh = h0 + bhl;
    const int b = bh / NH, h = bh % NH;
    const u16* Mh = Mb + (size_t)bhl * NN * NN;
    const u16* vhb = vth + (size_t)bh * HD * NN;
    const u16* vlb = vtl + (size_t)bh * HD * NN;

    const int w = tid >> 6, l = tid & 63;
    const int l15 = l & 15, kb4 = l >> 4;
    const int lrow = l >> 2, lch = (l & 3) * 8;

    f32x4 acc[4], accs;
    const f32x4 zero = {0.f, 0.f, 0.f, 0.f};
#pragma unroll
    for (int c = 0; c < 4; ++c) acc[c] = zero;
    accs = zero;
    s16x8 ones;
#pragma unroll
    for (int e = 0; e < 8; ++e) ones[e] = (short)0x3F80;   // bf16 1.0

    for (int k0 = 0; k0 < NN; k0 += 32) {
        {
            const int r = w * 16;                  // M rows: 4 waves x 16 = 64
            GLD16(&Mh[(size_t)(i0 + r + lrow) * NN + k0 + lch], &sM[r * 32]);
            const size_t vr = (size_t)(r + lrow) * NN + k0 + lch;
            GLD16(&vhb[vr], &sVh[r * 32]);
            GLD16(&vlb[vr], &sVl[r * 32]);
        }
        __syncthreads();

        s16x8 af, bh[4], bl[4];
        af = *(const s16x8*)&sM[(w * 16 + l15) * 32 + kb4 * 8];
#pragma unroll
        for (int f = 0; f < 4; ++f) {
            bh[f] = *(const s16x8*)&sVh[(f * 16 + l15) * 32 + kb4 * 8];
            bl[f] = *(const s16x8*)&sVl[(f * 16 + l15) * 32 + kb4 * 8];
        }
#pragma unroll
        for (int fc = 0; fc < 4; ++fc) {
            acc[fc] = __builtin_amdgcn_mfma_f32_16x16x32_bf16(
                af, bh[fc], acc[fc], 0, 0, 0);
            acc[fc] = __builtin_amdgcn_mfma_f32_16x16x32_bf16(
                af, bl[fc], acc[fc], 0, 0, 0);
        }
        accs = __builtin_amdgcn_mfma_f32_16x16x32_bf16(af, ones, accs, 0, 0, 0);
        __syncthreads();
    }

#pragma unroll
    for (int r = 0; r < 4; ++r) {
        const int gi = i0 + w * 16 + kb4 * 4 + r;
        const float inv = 1.0f / (accs[r] + 1e-9f);
        const size_t ob = (size_t)(b * NN + gi) * DIMC + h * HD;
#pragma unroll
        for (int fc = 0; fc < 4; ++fc) {
            const int gd = fc * 16 + l15;
            bfp s = splitf(acc[fc][r] * inv);
            aoh[ob + gd] = s.h;
            aol[ob + gd] = s.l;
        }
    }
}

// ---------------------------------------------------------------------------
extern "C" void kernel_launch(void* const* d_in, const int* in_sizes, int n_in,
                              void* d_out, int out_size, void* d_ws, size_t ws_size,
                              hipStream_t stream)
{
    const float* x      = (const float*)d_in[0];
    const float* qkv_w  = (const float*)d_in[1];
    const float* qkv_b  = (const float*)d_in[2];
    const float* proj_w = (const float*)d_in[3];
    const float* proj_b = (const float*)d_in[4];
    const float* lamb   = (const float*)d_in[5];
    const float* gamma  = (const float*)d_in[6];
    const float* delta  = (const float*)d_in[7];

    char* p = (char*)d_ws;
    u16* xh  = (u16*)p;                     p += (size_t)4096 * DIMC * 2;
    u16* xl  = (u16*)p;                     p += (size_t)4096 * DIMC * 2;
    u16* wh  = (u16*)p;                     p += (size_t)QKVC * DIMC * 2;
    u16* wl  = (u16*)p;                     p += (size_t)QKVC * DIMC * 2;
    u16* pwh = (u16*)p;                     p += (size_t)DIMC * DIMC * 2;
    u16* pwl = (u16*)p;                     p += (size_t)DIMC * DIMC * 2;
    u16* qh  = (u16*)p;                     p += (size_t)BHT * NN * HD * 2;
    u16* ql  = (u16*)p;                     p += (size_t)BHT * NN * HD * 2;
    u16* kh  = (u16*)p;                     p += (size_t)BHT * NN * HD * 2;
    u16* kl  = (u16*)p;                     p += (size_t)BHT * NN * HD * 2;
    u16* vth = (u16*)p;                     p += (size_t)BHT * HD * NN * 2;
    u16* vtl = (u16*)p;                     p += (size_t)BHT * HD * NN * 2;
    u16* aoh = (u16*)p;                     p += (size_t)4096 * DIMC * 2;
    u16* aol = (u16*)p;                     p += (size_t)4096 * DIMC * 2;
    const size_t fixed = (size_t)(p - (char*)d_ws);

    // per-head: S fp32 4MB (M bf16 aliases into it) + A bf16 2MB
    const size_t perh = (size_t)NN * NN * 4 + (size_t)NN * NN * 2;
    static const int choices[] = {48, 24, 16, 12, 8, 6, 4, 3, 2, 1};
    int CH = 1;
    for (int ci = 0; ci < 10; ++ci) {
        int c = choices[ci];
        if (fixed + (size_t)c * perh <= ws_size) { CH = c; break; }
    }

    float* Sb = (float*)p;                  p += (size_t)CH * NN * NN * 4;
    u16* Abf  = (u16*)p;                    p += (size_t)CH * NN * NN * 2;
    u16* Mb   = (u16*)Sb;                   // alias: S dead after softmax

    // 0) splits of inputs
    split_f2b<<<dim3((4096 * DIMC / 4 + 255) / 256), 256, 0, stream>>>(x, xh, xl, 4096 * DIMC / 4);
    split_f2b<<<dim3((QKVC * DIMC / 4 + 255) / 256), 256, 0, stream>>>(qkv_w, wh, wl, QKVC * DIMC / 4);
    split_f2b<<<dim3((DIMC * DIMC / 4 + 255) / 256), 256, 0, stream>>>(proj_w, pwh, pwl, DIMC * DIMC / 4);

    // 1) qkv GEMM fused: writes qh/ql/kh/kl (bh,n,64) and vth/vtl (bh,64,n)
    qkv_fused_mfma<<<dim3(QKVC / 128, 4096 / 128), 256, 0, stream>>>(
        xh, xl, wh, wl, qkv_b, qh, ql, kh, kl, vth, vtl);

    // 2..5) per chunk of heads
    for (int h0 = 0; h0 < BHT; h0 += CH) {
        qk_mfma<<<dim3(8, 8, CH), 256, 0, stream>>>(qh, ql, kh, kl, Sb, h0);
        softmax_w<<<dim3(CH * NN / 4), 256, 0, stream>>>(Sb, Abf);
        mpow_mfma<<<dim3(8, 8, CH), 256, 0, stream>>>(
            Abf, Mb, lamb, gamma, delta, h0);
        pv_mfma<<<dim3(16, CH), 256, 0, stream>>>(Mb, vth, vtl, aoh, aol, h0);
    }

    // 6) final = ao @ proj_w^T + proj_b
    gemm3_mfma<<<dim3(DIMC / 128, 4096 / 128), 256, 0, stream>>>(
        4096, DIMC, DIMC, aoh, aol, pwh, pwl, proj_b, (float*)d_out);
}